// Round 24
// baseline (39.832 us; speedup 1.0000x reference)
//
#include <hip/hip_runtime.h>
#include <stdint.h>

typedef __attribute__((ext_vector_type(4)))  int   i32x4;
typedef __attribute__((ext_vector_type(8)))  int   i32x8;
typedef __attribute__((ext_vector_type(16))) float f32x16;

#define NROWS 4096
#define DDIM  1024     // bytes per fp8 row
#define NKT   16       // K-tiles of 64 bytes
#define NB    32       // 128-row panels
#define NBLK  528      // NB*(NB+1)/2 triangular 128x128 tiles
#define COS_EPS 1e-8f
#define SCL   0x7F7F7F7F   // E8M0 = 127 -> scale 1.0

__device__ __forceinline__ void gload16(const uint8_t* g, uint8_t* l) {
  __builtin_amdgcn_global_load_lds(
      (const __attribute__((address_space(1))) uint32_t*)g,
      (__attribute__((address_space(3))) uint32_t*)l, 16, 0, 0);
}

__device__ __forceinline__ i32x8 cat8(i32x4 lo, i32x4 hi) {
  i32x8 r;
  r[0] = lo[0]; r[1] = lo[1]; r[2] = lo[2]; r[3] = lo[3];
  r[4] = hi[0]; r[5] = hi[1]; r[6] = hi[2]; r[7] = hi[3];
  return r;
}

// ---------------- prep: sq, 1/norm, fp8 e4m3 copy, zero out ----------------
extern "C" __global__ void __launch_bounds__(256) prep_kernel(
    const float* __restrict__ F, uint8_t* __restrict__ Fb,
    float* __restrict__ sq, float* __restrict__ rn, float* __restrict__ out) {
  if (blockIdx.x == 0 && threadIdx.x == 0) out[0] = 0.f;   // atomic target
  const int row  = blockIdx.x * 4 + (threadIdx.x >> 6);
  const int lane = threadIdx.x & 63;
  const float4* src = (const float4*)(F + (size_t)row * DDIM + lane * 16);
  float4 v[4];
#pragma unroll
  for (int i = 0; i < 4; ++i) v[i] = src[i];
  float s = 0.f;
#pragma unroll
  for (int i = 0; i < 4; ++i)
    s += v[i].x * v[i].x + v[i].y * v[i].y + v[i].z * v[i].z + v[i].w * v[i].w;
  uint32_t d[4];
#pragma unroll
  for (int i = 0; i < 4; ++i) {
    int w = __builtin_amdgcn_cvt_pk_fp8_f32(v[i].x, v[i].y, 0, false);
    w = __builtin_amdgcn_cvt_pk_fp8_f32(v[i].z, v[i].w, w, true);
    d[i] = (uint32_t)w;
  }
  *(uint4*)(Fb + (size_t)row * DDIM + lane * 16) = make_uint4(d[0], d[1], d[2], d[3]);
#pragma unroll
  for (int off = 32; off; off >>= 1) s += __shfl_down(s, off);
  if (lane == 0) {
    sq[row] = s;
    rn[row] = 1.0f / fmaxf(sqrtf(s), COS_EPS);
  }
}

// ---------------- fused gram: fp8 MX triangle, cross-iter read-ahead -------
// R22 geometry (528 tri blocks, 8 waves of 64x32, row-pair LDS map) with a
// 4-slot ring and REGISTER-PIPELINED fragments: iter kt issues ds_reads for
// tile kt+1 into the alternate reg set and MFMAs tile kt from regs read one
// iteration earlier. Hazards: STAGE(kt+3)->slot (kt-1)&3 (reads lgkm-retired
// before iter kt-1's end barrier); vmcnt(2) at iter kt retires through tile
// kt+2 -> after barrier, iter kt+1's RD(kt+2) is cross-wave safe.
extern "C" __global__ void __launch_bounds__(512, 4) gram_kernel(
    const uint8_t* __restrict__ Fb, const float* __restrict__ sq,
    const float* __restrict__ rn, const int* __restrict__ y,
    float* __restrict__ out) {
  __shared__ __align__(16) uint8_t As[4][8192];   // 128 rows x 64B per slot
  __shared__ __align__(16) uint8_t Bs[4][8192];
  __shared__ float wsum[8];

  // XCD-chunked bijection (528 = 8*66) + triangular staircase decode
  int s = (int)(blockIdx.x & 7) * 66 + (int)(blockIdx.x >> 3);
  int bi = 0, rem0 = s;
  while (rem0 >= NB - bi) { rem0 -= NB - bi; ++bi; }
  const int bj = bi + rem0;
  const bool diag = (bi == bj);

  const int tid  = threadIdx.x;
  const int lane = tid & 63;
  const int wid  = tid >> 6;
  const int wr   = wid >> 2;      // 0..1 : 64-row group
  const int wc   = wid & 3;       // 0..3 : 32-col group
  const int kg   = lane >> 5;
  const int r32  = lane & 31;

  // staging source decode (row-pair + granule-XOR map)
  const int hc   = (tid & 7) ^ ((tid >> 3) & 7);
  const int srow = 2 * (tid >> 3) + ((hc >> 2) & 1);   // 0..127
  const int scol = (hc & 3) * 16;
  const uint8_t* gA = Fb + (size_t)(bi * 128 + srow) * DDIM + scol;
  const uint8_t* gB = Fb + (size_t)(bj * 128 + srow) * DDIM + scol;
  uint8_t* ldsA = &As[0][0] + tid * 16;
  uint8_t* ldsB = &Bs[0][0] + tid * 16;

  // fragment read offsets (lo granule; hi = lo ^ 16)
  int offA0, offA1, offB1;
  {
    int R = wr * 64 + 0 * 32 + r32, u = R >> 1, h = R & 1;
    offA0 = u * 128 + (((h << 2) + 2 * kg) ^ (u & 7)) * 16;
    R = wr * 64 + 1 * 32 + r32; u = R >> 1; h = R & 1;
    offA1 = u * 128 + (((h << 2) + 2 * kg) ^ (u & 7)) * 16;
    R = wc * 32 + r32; u = R >> 1; h = R & 1;
    offB1 = u * 128 + (((h << 2) + 2 * kg) ^ (u & 7)) * 16;
  }

  f32x16 acc[2] = {};
  i32x4 p0_0, p0_1, p0_2, p0_3, p0_4, p0_5;   // reg set 0
  i32x4 p1_0, p1_1, p1_2, p1_3, p1_4, p1_5;   // reg set 1

#define STAGE(kt2) do {                                                     \
    const int _sl = (kt2) & 3;                                              \
    gload16(gA + (kt2) * 64, ldsA + _sl * 8192);                            \
    gload16(gB + (kt2) * 64, ldsB + _sl * 8192);                            \
  } while (0)

#define RD(set, kt1) do {                                                   \
    const uint8_t* _sa = &As[(kt1) & 3][0];                                 \
    const uint8_t* _sb = &Bs[(kt1) & 3][0];                                 \
    p##set##_0 = *(const i32x4*)(_sa + offA0);                              \
    p##set##_1 = *(const i32x4*)(_sa + (offA0 ^ 16));                       \
    p##set##_2 = *(const i32x4*)(_sa + offA1);                              \
    p##set##_3 = *(const i32x4*)(_sa + (offA1 ^ 16));                       \
    p##set##_4 = *(const i32x4*)(_sb + offB1);                              \
    p##set##_5 = *(const i32x4*)(_sb + (offB1 ^ 16));                       \
  } while (0)

#define MFMA2(set) do {                                                     \
    const i32x8 _A0 = cat8(p##set##_0, p##set##_1);                         \
    const i32x8 _A1 = cat8(p##set##_2, p##set##_3);                         \
    const i32x8 _B0 = cat8(p##set##_4, p##set##_5);                         \
    acc[0] = __builtin_amdgcn_mfma_scale_f32_32x32x64_f8f6f4(               \
        _A0, _B0, acc[0], 0, 0, 0, SCL, 0, SCL);                            \
    acc[1] = __builtin_amdgcn_mfma_scale_f32_32x32x64_f8f6f4(               \
        _A1, _B0, acc[1], 0, 0, 0, SCL, 0, SCL);                            \
  } while (0)

  // one pipelined iteration: set S holds tile k's frags; read k+1 into set N
#define ITER(S, N, k) do {                                                  \
    if ((k) + 3 < NKT) STAGE((k) + 3);                                      \
    if ((k) + 1 < NKT) {                                                    \
      RD(N, (k) + 1);                                                       \
      asm volatile("s_waitcnt lgkmcnt(6)");                                 \
    } else {                                                                \
      asm volatile("s_waitcnt lgkmcnt(0)");                                 \
    }                                                                       \
    __builtin_amdgcn_sched_barrier(0);                                      \
    MFMA2(S);                                                               \
    if ((k) + 3 < NKT)        asm volatile("s_waitcnt vmcnt(2)");           \
    else if ((k) == NKT - 3)  asm volatile("s_waitcnt vmcnt(0)");           \
    if ((k) < NKT - 1) {                                                    \
      __builtin_amdgcn_s_barrier();                                         \
      __builtin_amdgcn_sched_barrier(0);                                    \
    }                                                                       \
  } while (0)

  // prologue: tiles 0,1,2 in flight (6 loads); retire 0,1; read tile 0
  STAGE(0); STAGE(1); STAGE(2);
  asm volatile("s_waitcnt vmcnt(2)");
  __builtin_amdgcn_s_barrier();
  __builtin_amdgcn_sched_barrier(0);
  RD(0, 0);

#pragma unroll 1
  for (int kt = 0; kt < NKT; kt += 2) {
    ITER(0, 1, kt);
    ITER(1, 0, kt + 1);
  }

#undef STAGE
#undef RD
#undef MFMA2
#undef ITER

  // ---------- epilogue: triangle weights (32x32 C/D layout) ----------
  const int gj = bj * 128 + wc * 32 + r32;
  const float sqj = sq[gj], rnj = rn[gj];
  const int yj = y[gj];
  float lsum = 0.f;
#pragma unroll
  for (int mt = 0; mt < 2; ++mt) {
#pragma unroll
    for (int e = 0; e < 16; ++e) {
      const int gi = bi * 128 + wr * 64 + mt * 32 + (e & 3) + 8 * (e >> 2) + 4 * kg;
      const float g  = acc[mt][e];
      const float d2 = sq[gi] + sqj - 2.0f * g;
      const float dist = d2 > 0.f ? sqrtf(d2) : 0.f;
      const float sim  = g * rn[gi] * rnj;
      const float sgn  = (y[gi] == yj) ? 1.0f : -1.0f;
      float wgt;
      if (diag) wgt = (gj > gi) ? 2.0f : ((gj == gi) ? 1.0f : 0.0f);
      else      wgt = 2.0f;
      lsum += wgt * sgn * (dist - sim);
    }
  }
#pragma unroll
  for (int off = 32; off; off >>= 1) lsum += __shfl_down(lsum, off);
  if (lane == 0) wsum[wid] = lsum;
  __syncthreads();
  if (tid == 0) {
    float t = 0.f;
#pragma unroll
    for (int i = 0; i < 8; ++i) t += wsum[i];
    atomicAdd(out, t);
  }
}

extern "C" void kernel_launch(void* const* d_in, const int* in_sizes, int n_in,
                              void* d_out, int out_size, void* d_ws, size_t ws_size,
                              hipStream_t stream) {
  const float* F = (const float*)d_in[0];
  const int*   y = (const int*)d_in[1];
  float* out = (float*)d_out;

  uint8_t* Fb = (uint8_t*)d_ws;                               // 4 MB fp8
  float*  sq = (float*)((char*)d_ws + (size_t)NROWS * DDIM);
  float*  rn = sq + NROWS;

  prep_kernel<<<NROWS / 4, 256, 0, stream>>>(F, Fb, sq, rn, out);
  gram_kernel<<<NBLK, 512, 0, stream>>>(Fb, sq, rn, y, out);
}

// Round 25
// 34.143 us; speedup vs baseline: 1.1666x; 1.1666x over previous
//
#include <hip/hip_runtime.h>
#include <stdint.h>

typedef __attribute__((ext_vector_type(4)))  int   i32x4;
typedef __attribute__((ext_vector_type(8)))  int   i32x8;
typedef __attribute__((ext_vector_type(16))) float f32x16;

#define NROWS 4096
#define DDIM  1024     // bytes per fp8 row
#define NKT   16       // K-tiles of 64 bytes
#define NB    32       // 128-row panels
#define NBLK  528      // NB*(NB+1)/2 triangular 128x128 tiles
#define COS_EPS 1e-8f
#define SCL   0x7F7F7F7F   // E8M0 = 127 -> scale 1.0

__device__ __forceinline__ void gload16(const uint8_t* g, uint8_t* l) {
  __builtin_amdgcn_global_load_lds(
      (const __attribute__((address_space(1))) uint32_t*)g,
      (__attribute__((address_space(3))) uint32_t*)l, 16, 0, 0);
}

__device__ __forceinline__ i32x8 cat8(i32x4 lo, i32x4 hi) {
  i32x8 r;
  r[0] = lo[0]; r[1] = lo[1]; r[2] = lo[2]; r[3] = lo[3];
  r[4] = hi[0]; r[5] = hi[1]; r[6] = hi[2]; r[7] = hi[3];
  return r;
}

// ---------------- prep: sq, 1/norm, fp8 e4m3 copy, zero out ----------------
extern "C" __global__ void __launch_bounds__(256) prep_kernel(
    const float* __restrict__ F, uint8_t* __restrict__ Fb,
    float* __restrict__ sq, float* __restrict__ rn, float* __restrict__ out) {
  if (blockIdx.x == 0 && threadIdx.x == 0) out[0] = 0.f;   // atomic target
  const int row  = blockIdx.x * 4 + (threadIdx.x >> 6);
  const int lane = threadIdx.x & 63;
  const float4* src = (const float4*)(F + (size_t)row * DDIM + lane * 16);
  float4 v[4];
#pragma unroll
  for (int i = 0; i < 4; ++i) v[i] = src[i];
  float s = 0.f;
#pragma unroll
  for (int i = 0; i < 4; ++i)
    s += v[i].x * v[i].x + v[i].y * v[i].y + v[i].z * v[i].z + v[i].w * v[i].w;
  uint32_t d[4];
#pragma unroll
  for (int i = 0; i < 4; ++i) {
    int w = __builtin_amdgcn_cvt_pk_fp8_f32(v[i].x, v[i].y, 0, false);
    w = __builtin_amdgcn_cvt_pk_fp8_f32(v[i].z, v[i].w, w, true);
    d[i] = (uint32_t)w;
  }
  *(uint4*)(Fb + (size_t)row * DDIM + lane * 16) = make_uint4(d[0], d[1], d[2], d[3]);
#pragma unroll
  for (int off = 32; off; off >>= 1) s += __shfl_down(s, off);
  if (lane == 0) {
    sq[row] = s;
    rn[row] = 1.0f / fmaxf(sqrtf(s), COS_EPS);
  }
}

// ---------------- fused gram: fp8 MX triangle 128x128, 8 x 64x32 waves -----
// Best measured config (R22): 528 triangular blocks, 512 thr = 8 waves
// (2M x 4N), wave = 64x32 out. 3-slot LDS ring (48 KB), row-pair staging
// (full 64B-line coverage/gload), counted vmcnt(2), one barrier/K-tile,
// no setprio, fused atomic reduce.
extern "C" __global__ void __launch_bounds__(512, 4) gram_kernel(
    const uint8_t* __restrict__ Fb, const float* __restrict__ sq,
    const float* __restrict__ rn, const int* __restrict__ y,
    float* __restrict__ out) {
  __shared__ __align__(16) uint8_t As[3][8192];   // 128 rows x 64B per slot
  __shared__ __align__(16) uint8_t Bs[3][8192];
  __shared__ float wsum[8];

  // XCD-chunked bijection (528 = 8*66) + triangular staircase decode
  int s = (int)(blockIdx.x & 7) * 66 + (int)(blockIdx.x >> 3);
  int bi = 0, rem0 = s;
  while (rem0 >= NB - bi) { rem0 -= NB - bi; ++bi; }
  const int bj = bi + rem0;
  const bool diag = (bi == bj);

  const int tid  = threadIdx.x;
  const int lane = tid & 63;
  const int wid  = tid >> 6;
  const int wr   = wid >> 2;      // 0..1 : 64-row group
  const int wc   = wid & 3;       // 0..3 : 32-col group
  const int kg   = lane >> 5;
  const int r32  = lane & 31;

  // staging source decode (row-pair + granule-XOR map)
  const int hc   = (tid & 7) ^ ((tid >> 3) & 7);
  const int srow = 2 * (tid >> 3) + ((hc >> 2) & 1);   // 0..127
  const int scol = (hc & 3) * 16;
  const uint8_t* gA = Fb + (size_t)(bi * 128 + srow) * DDIM + scol;
  const uint8_t* gB = Fb + (size_t)(bj * 128 + srow) * DDIM + scol;
  uint8_t* ldsA = &As[0][0] + tid * 16;
  uint8_t* ldsB = &Bs[0][0] + tid * 16;

  // fragment read offsets (lo granule; hi = lo ^ 16)
  int offA[2], offB1;
#pragma unroll
  for (int mt = 0; mt < 2; ++mt) {
    const int R = wr * 64 + mt * 32 + r32;
    const int u = R >> 1, h = R & 1;
    offA[mt] = u * 128 + (((h << 2) + 2 * kg) ^ (u & 7)) * 16;
  }
  {
    const int R = wc * 32 + r32;
    const int u = R >> 1, h = R & 1;
    offB1 = u * 128 + (((h << 2) + 2 * kg) ^ (u & 7)) * 16;
  }

  f32x16 acc[2] = {};

#define STAGE(kt2) do {                                                     \
    const int _sl = (kt2) % 3;                                              \
    gload16(gA + (kt2) * 64, ldsA + _sl * 8192);                            \
    gload16(gB + (kt2) * 64, ldsB + _sl * 8192);                            \
  } while (0)

  // prologue: K-tiles 0,1 in flight (4 loads); wait tile 0 (leave 2)
  STAGE(0); STAGE(1);
  asm volatile("s_waitcnt vmcnt(2)");
  __builtin_amdgcn_s_barrier();
  __builtin_amdgcn_sched_barrier(0);

#pragma unroll 1
  for (int kt = 0; kt < NKT; ++kt) {
    const uint8_t* sa = &As[0][0] + (kt % 3) * 8192;
    const uint8_t* sb = &Bs[0][0] + (kt % 3) * 8192;

    const i32x8 A0 = cat8(*(const i32x4*)(sa + offA[0]),
                          *(const i32x4*)(sa + (offA[0] ^ 16)));
    const i32x8 A1 = cat8(*(const i32x4*)(sa + offA[1]),
                          *(const i32x4*)(sa + (offA[1] ^ 16)));
    const i32x8 B0 = cat8(*(const i32x4*)(sb + offB1),
                          *(const i32x4*)(sb + (offB1 ^ 16)));

    if (kt + 2 < NKT) STAGE(kt + 2);

    acc[0] = __builtin_amdgcn_mfma_scale_f32_32x32x64_f8f6f4(
        A0, B0, acc[0], 0, 0, 0, SCL, 0, SCL);
    acc[1] = __builtin_amdgcn_mfma_scale_f32_32x32x64_f8f6f4(
        A1, B0, acc[1], 0, 0, 0, SCL, 0, SCL);

    if (kt + 2 < NKT)       asm volatile("s_waitcnt vmcnt(2)");  // kt+1 landed
    else if (kt == NKT - 2) asm volatile("s_waitcnt vmcnt(0)");
    if (kt < NKT - 1) {
      __builtin_amdgcn_s_barrier();
      __builtin_amdgcn_sched_barrier(0);   // next-iter ds_reads stay below
    }
  }

#undef STAGE

  // ---------- epilogue: triangle weights (32x32 C/D layout) ----------
  const int gj = bj * 128 + wc * 32 + r32;
  const float sqj = sq[gj], rnj = rn[gj];
  const int yj = y[gj];
  float lsum = 0.f;
#pragma unroll
  for (int mt = 0; mt < 2; ++mt) {
#pragma unroll
    for (int e = 0; e < 16; ++e) {
      const int gi = bi * 128 + wr * 64 + mt * 32 + (e & 3) + 8 * (e >> 2) + 4 * kg;
      const float g  = acc[mt][e];
      const float d2 = sq[gi] + sqj - 2.0f * g;
      const float dist = d2 > 0.f ? sqrtf(d2) : 0.f;
      const float sim  = g * rn[gi] * rnj;
      const float sgn  = (y[gi] == yj) ? 1.0f : -1.0f;
      float wgt;
      if (diag) wgt = (gj > gi) ? 2.0f : ((gj == gi) ? 1.0f : 0.0f);
      else      wgt = 2.0f;
      lsum += wgt * sgn * (dist - sim);
    }
  }
#pragma unroll
  for (int off = 32; off; off >>= 1) lsum += __shfl_down(lsum, off);
  if (lane == 0) wsum[wid] = lsum;
  __syncthreads();
  if (tid == 0) {
    float t = 0.f;
#pragma unroll
    for (int i = 0; i < 8; ++i) t += wsum[i];
    atomicAdd(out, t);
  }
}

extern "C" void kernel_launch(void* const* d_in, const int* in_sizes, int n_in,
                              void* d_out, int out_size, void* d_ws, size_t ws_size,
                              hipStream_t stream) {
  const float* F = (const float*)d_in[0];
  const int*   y = (const int*)d_in[1];
  float* out = (float*)d_out;

  uint8_t* Fb = (uint8_t*)d_ws;                               // 4 MB fp8
  float*  sq = (float*)((char*)d_ws + (size_t)NROWS * DDIM);
  float*  rn = sq + NROWS;

  prep_kernel<<<NROWS / 4, 256, 0, stream>>>(F, Fb, sq, rn, out);
  gram_kernel<<<NBLK, 512, 0, stream>>>(Fb, sq, rn, y, out);
}